// Round 1
// baseline (3035.872 us; speedup 1.0000x reference)
//
#include <hip/hip_runtime.h>
#include <hip/hip_bf16.h>
#include <math.h>

#define BB 2
#define SS 2048
#define DD 1024
#define HH 16
#define HDIM 64
#define NT (BB*SS)      // 4096 tokens

// ---------------- fp32 tiled GEMM with bias: C[n][m] = sum_k A[n][k]*W[k][m] + bias[m]
// A: [NT][1024], W: [1024][M_DIM], C: [NT][M_DIM]. 64x64 tile, 256 thr, 4x4/thread, K-tile 16.
template<int M_DIM>
__global__ __launch_bounds__(256) void gemm_bias(const float* __restrict__ A,
                                                 const float* __restrict__ W,
                                                 const float* __restrict__ bias,
                                                 float* __restrict__ C) {
    __shared__ __align__(16) float As[16][68];   // [kk][r]  (A staged transposed)
    __shared__ __align__(16) float Bs[16][68];   // [kk][c]
    const int t  = threadIdx.x;
    const int n0 = blockIdx.x * 64;
    const int m0 = blockIdx.y * 64;
    const int r4 = (t >> 4) << 2;
    const int c4 = (t & 15) << 2;
    float acc[4][4] = {};

    for (int k0 = 0; k0 < 1024; k0 += 16) {
        __syncthreads();
        // stage A: 64 rows x 16 k  (global: 16 consecutive floats per row)
        #pragma unroll
        for (int rep = 0; rep < 4; ++rep) {
            int r  = (t >> 4) + rep * 16;
            int kk = t & 15;
            As[kk][r] = A[(size_t)(n0 + r) * 1024 + k0 + kk];
        }
        // stage B: 16 k x 64 cols (global: 64 consecutive floats per k-row)
        #pragma unroll
        for (int rep = 0; rep < 4; ++rep) {
            int kk = (t >> 6) + rep * 4;
            int c  = t & 63;
            Bs[kk][c] = W[(size_t)(k0 + kk) * M_DIM + m0 + c];
        }
        __syncthreads();
        #pragma unroll
        for (int kk = 0; kk < 16; ++kk) {
            float4 av = *(const float4*)&As[kk][r4];
            float4 bv = *(const float4*)&Bs[kk][c4];
            const float* ap = (const float*)&av;
            const float* bp = (const float*)&bv;
            #pragma unroll
            for (int i = 0; i < 4; ++i)
                #pragma unroll
                for (int j = 0; j < 4; ++j)
                    acc[i][j] += ap[i] * bp[j];
        }
    }
    #pragma unroll
    for (int i = 0; i < 4; ++i)
        #pragma unroll
        for (int j = 0; j < 4; ++j)
            C[(size_t)(n0 + r4 + i) * M_DIM + m0 + c4 + j] = acc[i][j] + bias[m0 + c4 + j];
}

// ---------------- flash-style causal attention, fp32
// qkv: [NT][3072] (cols: 0..1023 q, 1024..2047 k, 2048..3071 v; within each: h*64+d)
// ctx: [NT][1024]  (token-major, col = h*64+d)
// grid: (B*H, S/64); block 256 = 4 waves; wave handles 16 q-rows.
__global__ __launch_bounds__(256) void attn_kernel(const float* __restrict__ qkv,
                                                   float* __restrict__ ctx) {
    __shared__ float Ks[64][65];
    __shared__ float Vs[64][65];
    const int bh = blockIdx.x;       // 0..31
    const int qt = blockIdx.y;       // 0..31
    const int b  = bh >> 4;
    const int h  = bh & 15;
    const int t  = threadIdx.x;
    const int w  = t >> 6;
    const int lane = t & 63;
    const int qbase = qt * 64;
    const float scale = 0.125f;      // 1/sqrt(64)

    float q[16], m[16], l[16], o[16];
    #pragma unroll
    for (int i = 0; i < 16; ++i) {
        int row = qbase + w * 16 + i;
        q[i] = qkv[(size_t)(b * SS + row) * 3072 + h * 64 + lane];
        m[i] = -1e30f; l[i] = 0.f; o[i] = 0.f;
    }

    for (int kt = 0; kt <= qt; ++kt) {
        __syncthreads();
        // stage K,V tiles: 64 keys x 64 dims each; coalesced scalar loads
        #pragma unroll
        for (int rep = 0; rep < 16; ++rep) {
            int idx = rep * 256 + t;          // 0..4095
            int j = idx >> 6, d = idx & 63;
            size_t base = (size_t)(b * SS + kt * 64 + j) * 3072 + h * 64 + d;
            Ks[j][d] = qkv[base + 1024];
            Vs[j][d] = qkv[base + 2048];
        }
        __syncthreads();
        const bool diag = (kt == qt);
        #pragma unroll
        for (int i = 0; i < 16; ++i) {
            const int row = qbase + w * 16 + i;
            // QK: lane = key index within tile
            float s = 0.f;
            #pragma unroll 8
            for (int d = 0; d < 64; ++d)
                s += __shfl(q[i], d) * Ks[lane][d];
            s *= scale;
            if (diag && (kt * 64 + lane > row)) s = -1e30f;
            // tile max across 64 lanes
            float tmax = s;
            #pragma unroll
            for (int off = 32; off; off >>= 1)
                tmax = fmaxf(tmax, __shfl_xor(tmax, off));
            float m_new = fmaxf(m[i], tmax);
            float p = __expf(s - m_new);
            float psum = p;
            #pragma unroll
            for (int off = 32; off; off >>= 1)
                psum += __shfl_xor(psum, off);
            float alpha = __expf(m[i] - m_new);
            l[i] = l[i] * alpha + psum;
            o[i] = o[i] * alpha;
            // AV: lane = dim index
            #pragma unroll 8
            for (int j = 0; j < 64; ++j)
                o[i] += __shfl(p, j) * Vs[j][lane];
            m[i] = m_new;
        }
    }
    #pragma unroll
    for (int i = 0; i < 16; ++i) {
        int row = qbase + w * 16 + i;
        ctx[(size_t)(b * SS + row) * 1024 + h * 64 + lane] = o[i] / l[i];
    }
}

extern "C" void kernel_launch(void* const* d_in, const int* in_sizes, int n_in,
                              void* d_out, int out_size, void* d_ws, size_t ws_size,
                              hipStream_t stream) {
    const float* hs     = (const float*)d_in[0];   // [2,2048,1024]
    const float* w_attn = (const float*)d_in[1];   // [1024,3072]
    const float* b_attn = (const float*)d_in[2];   // [3072]
    const float* w_proj = (const float*)d_in[3];   // [1024,1024]
    const float* b_proj = (const float*)d_in[4];   // [1024]
    float* out = (float*)d_out;                    // [2,2048,1024]

    float* qkv = (float*)d_ws;                     // 4096*3072 fp32 = 48 MB
    float* ctx = qkv + (size_t)NT * 3072;          // 4096*1024 fp32 = 16 MB

    // 1) QKV projection
    gemm_bias<3072><<<dim3(NT / 64, 3072 / 64), 256, 0, stream>>>(hs, w_attn, b_attn, qkv);
    // 2) causal attention
    attn_kernel<<<dim3(BB * HH, SS / 64), 256, 0, stream>>>(qkv, ctx);
    // 3) output projection
    gemm_bias<1024><<<dim3(NT / 64, 1024 / 64), 256, 0, stream>>>(ctx, w_proj, b_proj, out);
}

// Round 2
// 158.564 us; speedup vs baseline: 19.1460x; 19.1460x over previous
//
#include <hip/hip_runtime.h>
#include <hip/hip_bf16.h>
#include <math.h>

typedef unsigned short u16;
typedef __attribute__((ext_vector_type(8))) short bf16x8;
typedef __attribute__((ext_vector_type(4))) float f32x4;

#define MFMA16(A,B,C) __builtin_amdgcn_mfma_f32_16x16x32_bf16(A,B,C,0,0,0)

#define BB 2
#define SS 2048
#define NT (BB*SS)

__device__ __forceinline__ u16 f2bf(float f) {
    union { float f; unsigned u; } c; c.f = f;
    unsigned r = c.u + 0x7FFF + ((c.u >> 16) & 1);
    return (u16)(r >> 16);
}
__device__ __forceinline__ float bf2f(u16 v) {
    union { unsigned u; float f; } c; c.u = ((unsigned)v) << 16;
    return c.f;
}

// ---------------- fp32 -> bf16 elementwise cast
__global__ __launch_bounds__(256) void cast_bf16(const float* __restrict__ in,
                                                 u16* __restrict__ out, int n) {
    int i = (blockIdx.x * 256 + threadIdx.x) * 4;
    if (i < n) {
        float4 v = *(const float4*)&in[i];
        ushort4 o;
        o.x = f2bf(v.x); o.y = f2bf(v.y); o.z = f2bf(v.z); o.w = f2bf(v.w);
        *(ushort4*)&out[i] = o;
    }
}

// ---------------- fp32 [1024][M] -> bf16 transposed [M][1024]
__global__ __launch_bounds__(256) void transpose_cast(const float* __restrict__ in,
                                                      u16* __restrict__ out, int M) {
    __shared__ float tile[64][65];
    const int k0 = blockIdx.x * 64, m0 = blockIdx.y * 64;
    const int t = threadIdx.x;
    #pragma unroll
    for (int rep = 0; rep < 16; ++rep) {
        int idx = rep * 256 + t;
        int kk = idx >> 6, mm = idx & 63;
        tile[kk][mm] = in[(size_t)(k0 + kk) * M + m0 + mm];
    }
    __syncthreads();
    #pragma unroll
    for (int rep = 0; rep < 16; ++rep) {
        int idx = rep * 256 + t;
        int mm = idx >> 6, kk = idx & 63;
        out[(size_t)(m0 + mm) * 1024 + k0 + kk] = f2bf(tile[kk][mm]);
    }
}

// ---------------- bf16 MFMA GEMM: C[n][m] = A[n][:] . BT[m][:] + bias[m]
// A: [NT][1024] bf16 row-major; BT: [MD][1024] bf16 row-major (W transposed).
// 128x128 tile, 256 thr = 4 waves (2x2), each wave 64x64 via 4x4 16x16x32 frags.
template<int MD, typename OutT>
__global__ __launch_bounds__(256) void gemm_bt(const u16* __restrict__ A,
                                               const u16* __restrict__ BT,
                                               const float* __restrict__ bias,
                                               OutT* __restrict__ C) {
    __shared__ u16 As[128 * 32];
    __shared__ u16 Bs[128 * 32];
    const int t = threadIdx.x;
    const int lane = t & 63;
    const int w = t >> 6;
    const int wr = (w >> 1) * 64, wc = (w & 1) * 64;
    const int ln = lane & 15, hi = lane >> 4;
    const int n0 = blockIdx.x * 128;
    const int m0 = blockIdx.y * 128;

    f32x4 acc[4][4];
    const f32x4 fz = {0.f, 0.f, 0.f, 0.f};
    #pragma unroll
    for (int i = 0; i < 4; ++i)
        #pragma unroll
        for (int j = 0; j < 4; ++j) acc[i][j] = fz;

    const int srow = t >> 2, schunk = t & 3;   // staging: row, 16B chunk of K

    for (int k0 = 0; k0 < 1024; k0 += 32) {
        __syncthreads();
        #pragma unroll
        for (int p = 0; p < 2; ++p) {
            int r = srow + p * 64;
            bf16x8 av = *(const bf16x8*)&A[(size_t)(n0 + r) * 1024 + k0 + schunk * 8];
            *(bf16x8*)&As[r * 32 + ((schunk ^ (r & 3)) << 3)] = av;
            bf16x8 bv = *(const bf16x8*)&BT[(size_t)(m0 + r) * 1024 + k0 + schunk * 8];
            *(bf16x8*)&Bs[r * 32 + ((schunk ^ (r & 3)) << 3)] = bv;
        }
        __syncthreads();
        bf16x8 af[4], bf[4];
        #pragma unroll
        for (int mi = 0; mi < 4; ++mi) {
            int r = wr + mi * 16 + ln;
            af[mi] = *(const bf16x8*)&As[r * 32 + ((hi ^ (r & 3)) << 3)];
        }
        #pragma unroll
        for (int ni = 0; ni < 4; ++ni) {
            int r = wc + ni * 16 + ln;
            bf[ni] = *(const bf16x8*)&Bs[r * 32 + ((hi ^ (r & 3)) << 3)];
        }
        #pragma unroll
        for (int mi = 0; mi < 4; ++mi)
            #pragma unroll
            for (int ni = 0; ni < 4; ++ni)
                acc[mi][ni] = MFMA16(af[mi], bf[ni], acc[mi][ni]);
    }

    #pragma unroll
    for (int mi = 0; mi < 4; ++mi) {
        #pragma unroll
        for (int ni = 0; ni < 4; ++ni) {
            int col = m0 + wc + ni * 16 + ln;
            float bv = bias[col];
            #pragma unroll
            for (int r = 0; r < 4; ++r) {
                int row = n0 + wr + mi * 16 + hi * 4 + r;
                float v = acc[mi][ni][r] + bv;
                if constexpr (sizeof(OutT) == 4) C[(size_t)row * MD + col] = v;
                else                             C[(size_t)row * MD + col] = (OutT)f2bf(v);
            }
        }
    }
}

// ---------------- MFMA flash attention (bf16)
// qkv: [NT][3072] bf16 (q|k|v, each col = h*64+d); ctx: [NT][1024] bf16.
// grid (32 bh, 32 qtile); 256 thr = 4 waves; wave w owns q rows qt*64+w*16..+15.
// S^T = K.Q^T (lane: qrow = lane&15); O^T = V^T.P^T (same lane->qrow; no P movement).
__global__ __launch_bounds__(256) void attn_mfma(const u16* __restrict__ qkv,
                                                 u16* __restrict__ ctx) {
    __shared__ u16 Ks[64 * 64];   // [key][d], 16B chunks XOR-swizzled by key&7
    __shared__ u16 Vt[64 * 68];   // [d][key], pad 4 keys (rows 136B, 8B-aligned)
    const int bh = blockIdx.x, qt = blockIdx.y;
    const int b = bh >> 4, h = bh & 15;
    const int t = threadIdx.x, w = t >> 6, lane = t & 63;
    const int ln = lane & 15, hi = lane >> 4;
    const int qrow = qt * 64 + w * 16 + ln;
    const size_t tok = (size_t)b * SS;

    // Q fragments (B-operand of S^T): reg i = Q[qrow][t2*32+hi*8+i] * 1/8
    bf16x8 qb[2];
    #pragma unroll
    for (int t2 = 0; t2 < 2; ++t2) {
        bf16x8 v = *(const bf16x8*)&qkv[(tok + qrow) * 3072 + h * 64 + t2 * 32 + hi * 8];
        #pragma unroll
        for (int i = 0; i < 8; ++i)
            v[i] = (short)f2bf(bf2f((u16)v[i]) * 0.125f);
        qb[t2] = v;
    }

    float m_run = -1e30f, l_run = 0.f;
    f32x4 o[4];
    const f32x4 fz = {0.f, 0.f, 0.f, 0.f};
    #pragma unroll
    for (int i = 0; i < 4; ++i) o[i] = fz;

    const int skey = t >> 3;     // 0..31 (+32 on pass 1)
    const int sch  = t & 7;      // 16B chunk

    for (int kt = 0; kt <= qt; ++kt) {
        __syncthreads();
        #pragma unroll
        for (int p = 0; p < 2; ++p) {
            int key = skey + p * 32;
            size_t g = (tok + kt * 64 + key) * 3072 + h * 64;
            bf16x8 kv = *(const bf16x8*)&qkv[g + 1024 + sch * 8];
            *(bf16x8*)&Ks[key * 64 + ((sch ^ (key & 7)) << 3)] = kv;
            bf16x8 vv = *(const bf16x8*)&qkv[g + 2048 + sch * 8];
            #pragma unroll
            for (int j = 0; j < 8; ++j)
                Vt[(sch * 8 + j) * 68 + key] = (u16)vv[j];
        }
        __syncthreads();

        // S^T = K . Q^T : 4 key sub-tiles of 16
        f32x4 sacc[4];
        #pragma unroll
        for (int s = 0; s < 4; ++s) {
            int key = s * 16 + ln;
            f32x4 a = fz;
            #pragma unroll
            for (int t2 = 0; t2 < 2; ++t2) {
                bf16x8 kf = *(const bf16x8*)&Ks[key * 64 + (((t2 * 4 + hi) ^ (key & 7)) << 3)];
                a = MFMA16(kf, qb[t2], a);
            }
            sacc[s] = a;
        }

        // mask + online softmax (lane owns one q-row; reduce over hi via 2 shfls)
        float p_[16];
        float mloc = -1e30f;
        #pragma unroll
        for (int s = 0; s < 4; ++s)
            #pragma unroll
            for (int r = 0; r < 4; ++r) {
                int keyg = kt * 64 + s * 16 + hi * 4 + r;
                float v = (keyg <= qrow) ? sacc[s][r] : -1e30f;
                p_[s * 4 + r] = v;
                mloc = fmaxf(mloc, v);
            }
        mloc = fmaxf(mloc, __shfl_xor(mloc, 16));
        mloc = fmaxf(mloc, __shfl_xor(mloc, 32));
        float m_new = fmaxf(m_run, mloc);
        float alpha = __expf(m_run - m_new);
        float lsum = 0.f;
        #pragma unroll
        for (int i = 0; i < 16; ++i) {
            float e = __expf(p_[i] - m_new);
            p_[i] = e;
            lsum += e;
        }
        lsum += __shfl_xor(lsum, 16);
        lsum += __shfl_xor(lsum, 32);
        l_run = l_run * alpha + lsum;
        m_run = m_new;
        #pragma unroll
        for (int dt = 0; dt < 4; ++dt) o[dt] *= alpha;

        // P -> bf16 A/B fragment (keys follow the same k-map as V reads below)
        bf16x8 pa[2];
        #pragma unroll
        for (int k2 = 0; k2 < 2; ++k2)
            #pragma unroll
            for (int i = 0; i < 8; ++i)
                pa[k2][i] = (short)f2bf(p_[k2 * 8 + i]);

        // O^T += V^T . P^T
        #pragma unroll
        for (int dt = 0; dt < 4; ++dt) {
            const int drow = (dt * 16 + ln) * 68;
            #pragma unroll
            for (int k2 = 0; k2 < 2; ++k2) {
                const u16* vp = &Vt[drow + k2 * 32 + hi * 4];
                ushort4 lo4 = *(const ushort4*)vp;
                ushort4 hi4 = *(const ushort4*)(vp + 16);
                bf16x8 va;
                va[0] = (short)lo4.x; va[1] = (short)lo4.y; va[2] = (short)lo4.z; va[3] = (short)lo4.w;
                va[4] = (short)hi4.x; va[5] = (short)hi4.y; va[6] = (short)hi4.z; va[7] = (short)hi4.w;
                o[dt] = MFMA16(va, pa[k2], o[dt]);
            }
        }
    }

    // epilogue: lane owns qrow = ln; d = dt*16 + hi*4 + r
    float inv = 1.f / l_run;
    #pragma unroll
    for (int dt = 0; dt < 4; ++dt) {
        ushort4 ov;
        ov.x = f2bf(o[dt][0] * inv);
        ov.y = f2bf(o[dt][1] * inv);
        ov.z = f2bf(o[dt][2] * inv);
        ov.w = f2bf(o[dt][3] * inv);
        *(ushort4*)&ctx[(tok + qrow) * 1024 + h * 64 + dt * 16 + hi * 4] = ov;
    }
}

extern "C" void kernel_launch(void* const* d_in, const int* in_sizes, int n_in,
                              void* d_out, int out_size, void* d_ws, size_t ws_size,
                              hipStream_t stream) {
    const float* hs     = (const float*)d_in[0];   // [2,2048,1024]
    const float* w_attn = (const float*)d_in[1];   // [1024,3072]
    const float* b_attn = (const float*)d_in[2];   // [3072]
    const float* w_proj = (const float*)d_in[3];   // [1024,1024]
    const float* b_proj = (const float*)d_in[4];   // [1024]
    float* out = (float*)d_out;                    // [2,2048,1024] fp32

    char* ws = (char*)d_ws;
    u16* hsb  = (u16*)ws;                          // 8 MB
    u16* waT  = (u16*)(ws + ((size_t)8  << 20));   // 6 MB  [3072][1024]
    u16* wpT  = (u16*)(ws + ((size_t)14 << 20));   // 2 MB  [1024][1024]
    u16* qkvb = (u16*)(ws + ((size_t)16 << 20));   // 24 MB [4096][3072]
    u16* ctxb = (u16*)(ws + ((size_t)40 << 20));   // 8 MB  [4096][1024]

    cast_bf16<<<4096, 256, 0, stream>>>(hs, hsb, NT * 1024);
    transpose_cast<<<dim3(16, 48), 256, 0, stream>>>(w_attn, waT, 3072);
    transpose_cast<<<dim3(16, 16), 256, 0, stream>>>(w_proj, wpT, 1024);

    gemm_bt<3072, u16><<<dim3(NT / 128, 3072 / 128), 256, 0, stream>>>(hsb, waT, b_attn, qkvb);
    attn_mfma<<<dim3(BB * 16, SS / 64), 256, 0, stream>>>(qkvb, ctxb);
    gemm_bt<1024, float><<<dim3(NT / 128, 1024 / 128), 256, 0, stream>>>(ctxb, wpT, b_proj, out);
}

// Round 4
// 123.313 us; speedup vs baseline: 24.6193x; 1.2859x over previous
//
#include <hip/hip_runtime.h>
#include <hip/hip_bf16.h>
#include <math.h>
#include <stdint.h>

typedef unsigned short u16;
typedef __attribute__((ext_vector_type(8))) short bf16x8;
typedef __attribute__((ext_vector_type(4))) float f32x4;

#define MFMA16(A,B,C) __builtin_amdgcn_mfma_f32_16x16x32_bf16(A,B,C,0,0,0)

#define BB 2
#define SS 2048
#define NT (BB*SS)

__device__ __forceinline__ u16 f2bf(float f) {
    union { float f; unsigned u; } c; c.f = f;
    unsigned r = c.u + 0x7FFF + ((c.u >> 16) & 1);
    return (u16)(r >> 16);
}
__device__ __forceinline__ float bf2f(u16 v) {
    union { unsigned u; float f; } c; c.u = ((unsigned)v) << 16;
    return c.f;
}

// async global->LDS, 16B per lane. LDS dest = wave-uniform base + lane*16B.
__device__ __forceinline__ void gl_lds16(const u16* g, u16* l) {
    __builtin_amdgcn_global_load_lds(
        (const __attribute__((address_space(1))) void*)(uintptr_t)g,
        (__attribute__((address_space(3))) void*)(uintptr_t)l, 16, 0, 0);
}

// ---------------- fp32 -> bf16 elementwise cast
__global__ __launch_bounds__(256) void cast_bf16(const float* __restrict__ in,
                                                 u16* __restrict__ out, int n) {
    int i = (blockIdx.x * 256 + threadIdx.x) * 4;
    if (i < n) {
        float4 v = *(const float4*)&in[i];
        ushort4 o;
        o.x = f2bf(v.x); o.y = f2bf(v.y); o.z = f2bf(v.z); o.w = f2bf(v.w);
        *(ushort4*)&out[i] = o;
    }
}

// ---------------- fp32 [1024][M] -> bf16 transposed [M][1024]
__global__ __launch_bounds__(256) void transpose_cast(const float* __restrict__ in,
                                                      u16* __restrict__ out, int M) {
    __shared__ float tile[64][65];
    const int k0 = blockIdx.x * 64, m0 = blockIdx.y * 64;
    const int t = threadIdx.x;
    #pragma unroll
    for (int rep = 0; rep < 16; ++rep) {
        int idx = rep * 256 + t;
        int kk = idx >> 6, mm = idx & 63;
        tile[kk][mm] = in[(size_t)(k0 + kk) * M + m0 + mm];
    }
    __syncthreads();
    #pragma unroll
    for (int rep = 0; rep < 16; ++rep) {
        int idx = rep * 256 + t;
        int mm = idx >> 6, kk = idx & 63;
        out[(size_t)(m0 + mm) * 1024 + k0 + kk] = f2bf(tile[kk][mm]);
    }
}

// ---------------- bf16 MFMA GEMM with global_load_lds staging (m97 pattern)
// C[n][m] = A[n][:] . BT[m][:] + bias[m]; 128x128 tile, 4 waves, 4x4 frags/wave.
// LDS linear [row][4 chunks of 8 u16]; LDS chunk c holds global chunk c^(row&3)
// (pre-swizzled per-lane source); reads XOR the same involution.
template<int MD, typename OutT>
__global__ __launch_bounds__(256) void gemm_bt(const u16* __restrict__ A,
                                               const u16* __restrict__ BT,
                                               const float* __restrict__ bias,
                                               OutT* __restrict__ C) {
    __shared__ u16 As[128 * 32];
    __shared__ u16 Bs[128 * 32];
    const int t = threadIdx.x;
    const int lane = t & 63;
    const int w = t >> 6;
    const int wr = (w >> 1) * 64, wc = (w & 1) * 64;
    const int ln = lane & 15, hi = lane >> 4;
    const int n0 = blockIdx.x * 128;
    const int m0 = blockIdx.y * 128;

    f32x4 acc[4][4];
    const f32x4 fz = {0.f, 0.f, 0.f, 0.f};
    #pragma unroll
    for (int i = 0; i < 4; ++i)
        #pragma unroll
        for (int j = 0; j < 4; ++j) acc[i][j] = fz;

    const int srow_in = lane >> 2;   // 0..15 within 16-row group
    const int schunk  = lane & 3;

    for (int k0 = 0; k0 < 1024; k0 += 32) {
        __syncthreads();
        #pragma unroll
        for (int p = 0; p < 2; ++p) {
            int q   = w * 2 + p;                 // 0..7: which 16-row group
            int row = q * 16 + srow_in;
            int cg  = schunk ^ (row & 3);        // pre-swizzled source chunk
            gl_lds16(&A [(size_t)(n0 + row) * 1024 + k0 + cg * 8], &As[q * 512]);
            gl_lds16(&BT[(size_t)(m0 + row) * 1024 + k0 + cg * 8], &Bs[q * 512]);
        }
        __syncthreads();
        bf16x8 af[4], bf[4];
        #pragma unroll
        for (int mi = 0; mi < 4; ++mi) {
            int r = wr + mi * 16 + ln;
            af[mi] = *(const bf16x8*)&As[r * 32 + ((hi ^ (r & 3)) << 3)];
        }
        #pragma unroll
        for (int ni = 0; ni < 4; ++ni) {
            int r = wc + ni * 16 + ln;
            bf[ni] = *(const bf16x8*)&Bs[r * 32 + ((hi ^ (r & 3)) << 3)];
        }
        #pragma unroll
        for (int mi = 0; mi < 4; ++mi)
            #pragma unroll
            for (int ni = 0; ni < 4; ++ni)
                acc[mi][ni] = MFMA16(af[mi], bf[ni], acc[mi][ni]);
    }

    #pragma unroll
    for (int mi = 0; mi < 4; ++mi) {
        #pragma unroll
        for (int ni = 0; ni < 4; ++ni) {
            int col = m0 + wc + ni * 16 + ln;
            float bv = bias[col];
            #pragma unroll
            for (int r = 0; r < 4; ++r) {
                int row = n0 + wr + mi * 16 + hi * 4 + r;
                float v = acc[mi][ni][r] + bv;
                if constexpr (sizeof(OutT) == 4) C[(size_t)row * MD + col] = v;
                else                             C[(size_t)row * MD + col] = (OutT)f2bf(v);
            }
        }
    }
}

// ---------------- MFMA flash attention (bf16)
// K staged via global_load_lds (XOR-involution layout); V staged via the
// round-2-proven register path into transposed Vt (scalar writes).
// S^T = K.Q^T ; O^T = V^T.P^T (lane owns one q-row; P stays in-lane).
__global__ __launch_bounds__(256) void attn_mfma(const u16* __restrict__ qkv,
                                                 u16* __restrict__ ctx) {
    __shared__ u16 Ks[64 * 64];   // [key][8 chunks of 8 u16], chunk c = global c^(key&7)
    __shared__ u16 Vt[64 * 68];   // [d][key], pad 4
    const int bh = blockIdx.x;
    const int qt = 31 - blockIdx.y;          // longest-first for LPT balance
    const int b = bh >> 4, h = bh & 15;
    const int t = threadIdx.x, w = t >> 6, lane = t & 63;
    const int ln = lane & 15, hi = lane >> 4;
    const int qrow = qt * 64 + w * 16 + ln;
    const size_t tok = (size_t)b * SS;

    // Q fragment (B operand of S^T): k = t2*32 + hi*8 + i, scaled by 1/8
    bf16x8 qb[2];
    #pragma unroll
    for (int t2 = 0; t2 < 2; ++t2) {
        bf16x8 v = *(const bf16x8*)&qkv[(tok + qrow) * 3072 + h * 64 + t2 * 32 + hi * 8];
        #pragma unroll
        for (int i = 0; i < 8; ++i)
            v[i] = (short)f2bf(bf2f((u16)v[i]) * 0.125f);
        qb[t2] = v;
    }

    float m_run = -1e30f, l_run = 0.f;
    f32x4 o[4];
    const f32x4 fz = {0.f, 0.f, 0.f, 0.f};
    #pragma unroll
    for (int i = 0; i < 4; ++i) o[i] = fz;

    // staging lane maps
    const int kkey_l = w * 8 + (lane >> 3);   // K: + p*32
    const int ksch   = lane & 7;
    const int skey   = t >> 3;                // V: 0..31, + p*32
    const int sch    = t & 7;

    for (int kt = 0; kt <= qt; ++kt) {
        __syncthreads();
        const size_t kvb = (tok + kt * 64) * 3072 + h * 64;
        #pragma unroll
        for (int p = 0; p < 2; ++p) {
            // K: async DMA, wave-uniform LDS base + lane*16B
            int kk = p * 32 + kkey_l;
            gl_lds16(&qkv[kvb + (size_t)kk * 3072 + 1024 + ((ksch ^ (kk & 7)) << 3)],
                     &Ks[(p * 32 + w * 8) * 64]);
            // V: register-staged transpose into Vt (round-2 proven path)
            int key = p * 32 + skey;
            bf16x8 vv = *(const bf16x8*)&qkv[kvb + (size_t)key * 3072 + 2048 + sch * 8];
            #pragma unroll
            for (int j = 0; j < 8; ++j)
                Vt[(sch * 8 + j) * 68 + key] = (u16)vv[j];
        }
        __syncthreads();

        // S^T = K . Q^T : 4 key sub-tiles of 16
        f32x4 sacc[4];
        #pragma unroll
        for (int s = 0; s < 4; ++s) {
            int key = s * 16 + ln;
            f32x4 a = fz;
            #pragma unroll
            for (int t2 = 0; t2 < 2; ++t2) {
                bf16x8 kf = *(const bf16x8*)&Ks[key * 64 + (((t2 * 4 + hi) ^ (key & 7)) << 3)];
                a = MFMA16(kf, qb[t2], a);
            }
            sacc[s] = a;
        }

        // online softmax (lane owns one q-row; reduce over hi via 2 shfls)
        float p_[16];
        float mloc = -1e30f;
        if (kt == qt) {
            #pragma unroll
            for (int s = 0; s < 4; ++s)
                #pragma unroll
                for (int r = 0; r < 4; ++r) {
                    int keyg = kt * 64 + s * 16 + hi * 4 + r;
                    float v = (keyg <= qrow) ? sacc[s][r] : -1e30f;
                    p_[s * 4 + r] = v;
                    mloc = fmaxf(mloc, v);
                }
        } else {
            #pragma unroll
            for (int s = 0; s < 4; ++s)
                #pragma unroll
                for (int r = 0; r < 4; ++r) {
                    float v = sacc[s][r];
                    p_[s * 4 + r] = v;
                    mloc = fmaxf(mloc, v);
                }
        }
        mloc = fmaxf(mloc, __shfl_xor(mloc, 16));
        mloc = fmaxf(mloc, __shfl_xor(mloc, 32));
        float m_new = fmaxf(m_run, mloc);
        float alpha = __expf(m_run - m_new);
        float lsum = 0.f;
        #pragma unroll
        for (int i = 0; i < 16; ++i) {
            float e = __expf(p_[i] - m_new);
            p_[i] = e;
            lsum += e;
        }
        lsum += __shfl_xor(lsum, 16);
        lsum += __shfl_xor(lsum, 32);
        l_run = l_run * alpha + lsum;
        m_run = m_new;
        #pragma unroll
        for (int dt = 0; dt < 4; ++dt) o[dt] *= alpha;

        // P -> bf16 fragments via packed convert (identity key bijection)
        bf16x8 pa[2];
        #pragma unroll
        for (int k2 = 0; k2 < 2; ++k2) {
            union { unsigned wd[4]; bf16x8 v; } pu;
            #pragma unroll
            for (int qi = 0; qi < 4; ++qi)
                asm("v_cvt_pk_bf16_f32 %0, %1, %2"
                    : "=v"(pu.wd[qi])
                    : "v"(p_[k2 * 8 + 2 * qi]), "v"(p_[k2 * 8 + 2 * qi + 1]));
            pa[k2] = pu.v;
        }

        // O^T += V^T . P^T  (V^T fragment from Vt: keys k2*32 + hi*4 + i + 16*(i>>2))
        #pragma unroll
        for (int dt = 0; dt < 4; ++dt) {
            const int drow = (dt * 16 + ln) * 68;
            #pragma unroll
            for (int k2 = 0; k2 < 2; ++k2) {
                const u16* vp = &Vt[drow + k2 * 32 + hi * 4];
                ushort4 lo4 = *(const ushort4*)vp;
                ushort4 hi4 = *(const ushort4*)(vp + 16);
                bf16x8 va;
                va[0] = (short)lo4.x; va[1] = (short)lo4.y; va[2] = (short)lo4.z; va[3] = (short)lo4.w;
                va[4] = (short)hi4.x; va[5] = (short)hi4.y; va[6] = (short)hi4.z; va[7] = (short)hi4.w;
                o[dt] = MFMA16(va, pa[k2], o[dt]);
            }
        }
    }

    // epilogue: lane owns qrow; d = dt*16 + hi*4 + r
    float inv = 1.f / l_run;
    #pragma unroll
    for (int dt = 0; dt < 4; ++dt) {
        ushort4 ov;
        ov.x = f2bf(o[dt][0] * inv);
        ov.y = f2bf(o[dt][1] * inv);
        ov.z = f2bf(o[dt][2] * inv);
        ov.w = f2bf(o[dt][3] * inv);
        *(ushort4*)&ctx[(tok + qrow) * 1024 + h * 64 + dt * 16 + hi * 4] = ov;
    }
}

extern "C" void kernel_launch(void* const* d_in, const int* in_sizes, int n_in,
                              void* d_out, int out_size, void* d_ws, size_t ws_size,
                              hipStream_t stream) {
    const float* hs     = (const float*)d_in[0];   // [2,2048,1024]
    const float* w_attn = (const float*)d_in[1];   // [1024,3072]
    const float* b_attn = (const float*)d_in[2];   // [3072]
    const float* w_proj = (const float*)d_in[3];   // [1024,1024]
    const float* b_proj = (const float*)d_in[4];   // [1024]
    float* out = (float*)d_out;                    // [2,2048,1024] fp32

    char* ws = (char*)d_ws;
    u16* hsb  = (u16*)ws;                          // 8 MB
    u16* waT  = (u16*)(ws + ((size_t)8  << 20));   // 6 MB  [3072][1024]
    u16* wpT  = (u16*)(ws + ((size_t)14 << 20));   // 2 MB  [1024][1024]
    u16* qkvb = (u16*)(ws + ((size_t)16 << 20));   // 24 MB [4096][3072]
    u16* ctxb = (u16*)(ws + ((size_t)40 << 20));   // 8 MB  [4096][1024]

    cast_bf16<<<4096, 256, 0, stream>>>(hs, hsb, NT * 1024);
    transpose_cast<<<dim3(16, 48), 256, 0, stream>>>(w_attn, waT, 3072);
    transpose_cast<<<dim3(16, 16), 256, 0, stream>>>(w_proj, wpT, 1024);

    gemm_bt<3072, u16><<<dim3(NT / 128, 3072 / 128), 256, 0, stream>>>(hsb, waT, b_attn, qkvb);
    attn_mfma<<<dim3(BB * 16, SS / 64), 256, 0, stream>>>(qkvb, ctxb);
    gemm_bt<1024, float><<<dim3(NT / 128, 1024 / 128), 256, 0, stream>>>(ctxb, wpT, b_proj, out);
}

// Round 5
// 118.667 us; speedup vs baseline: 25.5832x; 1.0392x over previous
//
#include <hip/hip_runtime.h>
#include <hip/hip_bf16.h>
#include <math.h>
#include <stdint.h>

typedef unsigned short u16;
typedef __attribute__((ext_vector_type(8))) short bf16x8;
typedef __attribute__((ext_vector_type(4))) float f32x4;

#define MFMA16(A,B,C) __builtin_amdgcn_mfma_f32_16x16x32_bf16(A,B,C,0,0,0)

#define BB 2
#define SS 2048
#define NT (BB*SS)

__device__ __forceinline__ u16 f2bf(float f) {
    union { float f; unsigned u; } c; c.f = f;
    unsigned r = c.u + 0x7FFF + ((c.u >> 16) & 1);
    return (u16)(r >> 16);
}
__device__ __forceinline__ float bf2f(u16 v) {
    union { unsigned u; float f; } c; c.u = ((unsigned)v) << 16;
    return c.f;
}

// async global->LDS, 16B per lane. LDS dest = wave-uniform base + lane*16B.
__device__ __forceinline__ void gl_lds16(const u16* g, u16* l) {
    __builtin_amdgcn_global_load_lds(
        (const __attribute__((address_space(1))) void*)(uintptr_t)g,
        (__attribute__((address_space(3))) void*)(uintptr_t)l, 16, 0, 0);
}

// ---------------- fp32 -> bf16 elementwise cast
__global__ __launch_bounds__(256) void cast_bf16(const float* __restrict__ in,
                                                 u16* __restrict__ out, int n) {
    int i = (blockIdx.x * 256 + threadIdx.x) * 4;
    if (i < n) {
        float4 v = *(const float4*)&in[i];
        ushort4 o;
        o.x = f2bf(v.x); o.y = f2bf(v.y); o.z = f2bf(v.z); o.w = f2bf(v.w);
        *(ushort4*)&out[i] = o;
    }
}

// ---------------- fp32 [1024][M] -> bf16 transposed [M][1024]
__global__ __launch_bounds__(256) void transpose_cast(const float* __restrict__ in,
                                                      u16* __restrict__ out, int M) {
    __shared__ float tile[64][65];
    const int k0 = blockIdx.x * 64, m0 = blockIdx.y * 64;
    const int t = threadIdx.x;
    #pragma unroll
    for (int rep = 0; rep < 16; ++rep) {
        int idx = rep * 256 + t;
        int kk = idx >> 6, mm = idx & 63;
        tile[kk][mm] = in[(size_t)(k0 + kk) * M + m0 + mm];
    }
    __syncthreads();
    #pragma unroll
    for (int rep = 0; rep < 16; ++rep) {
        int idx = rep * 256 + t;
        int mm = idx >> 6, kk = idx & 63;
        out[(size_t)(m0 + mm) * 1024 + k0 + kk] = f2bf(tile[kk][mm]);
    }
}

// ---------------- V pre-transpose: qkvb V-part [token][h*64+d] -> vtg[bh*64+d][token]
// grid (32 bh, 32 token-tiles); plain (unswizzled) output layout.
__global__ __launch_bounds__(256) void transpose_v(const u16* __restrict__ qkvb,
                                                   u16* __restrict__ vtg) {
    __shared__ u16 tile[64][72];   // [token][d], 16B-aligned rows
    const int bh = blockIdx.x, kt = blockIdx.y;
    const int b = bh >> 4, h = bh & 15;
    const int t = threadIdx.x;
    const int tt = t >> 2;
    #pragma unroll
    for (int r = 0; r < 2; ++r) {
        int c = (t & 3) + r * 4;   // 16B chunk of the 64-d row
        *(bf16x8*)&tile[tt][c * 8] =
            *(const bf16x8*)&qkvb[(size_t)(b * SS + kt * 64 + tt) * 3072 + 2048 + h * 64 + c * 8];
    }
    __syncthreads();
    const int d = t >> 2;
    #pragma unroll
    for (int r = 0; r < 2; ++r) {
        int c16 = (t & 3) + r * 4;  // out 16B chunk = tokens c16*8..+7
        ushort4 o0, o1;
        o0.x = tile[c16 * 8 + 0][d]; o0.y = tile[c16 * 8 + 1][d];
        o0.z = tile[c16 * 8 + 2][d]; o0.w = tile[c16 * 8 + 3][d];
        o1.x = tile[c16 * 8 + 4][d]; o1.y = tile[c16 * 8 + 5][d];
        o1.z = tile[c16 * 8 + 6][d]; o1.w = tile[c16 * 8 + 7][d];
        u16* dst = &vtg[(size_t)(bh * 64 + d) * SS + kt * 64 + c16 * 8];
        *(ushort4*)dst = o0;
        *(ushort4*)(dst + 4) = o1;
    }
}

// ---------------- bf16 MFMA GEMM with global_load_lds staging (m97 pattern)
template<int MD, typename OutT>
__global__ __launch_bounds__(256) void gemm_bt(const u16* __restrict__ A,
                                               const u16* __restrict__ BT,
                                               const float* __restrict__ bias,
                                               OutT* __restrict__ C) {
    __shared__ u16 As[128 * 32];
    __shared__ u16 Bs[128 * 32];
    const int t = threadIdx.x;
    const int lane = t & 63;
    const int w = t >> 6;
    const int wr = (w >> 1) * 64, wc = (w & 1) * 64;
    const int ln = lane & 15, hi = lane >> 4;
    const int n0 = blockIdx.x * 128;
    const int m0 = blockIdx.y * 128;

    f32x4 acc[4][4];
    const f32x4 fz = {0.f, 0.f, 0.f, 0.f};
    #pragma unroll
    for (int i = 0; i < 4; ++i)
        #pragma unroll
        for (int j = 0; j < 4; ++j) acc[i][j] = fz;

    const int srow_in = lane >> 2;
    const int schunk  = lane & 3;

    for (int k0 = 0; k0 < 1024; k0 += 32) {
        __syncthreads();
        #pragma unroll
        for (int p = 0; p < 2; ++p) {
            int q   = w * 2 + p;
            int row = q * 16 + srow_in;
            int cg  = schunk ^ (row & 3);
            gl_lds16(&A [(size_t)(n0 + row) * 1024 + k0 + cg * 8], &As[q * 512]);
            gl_lds16(&BT[(size_t)(m0 + row) * 1024 + k0 + cg * 8], &Bs[q * 512]);
        }
        __syncthreads();
        bf16x8 af[4], bf[4];
        #pragma unroll
        for (int mi = 0; mi < 4; ++mi) {
            int r = wr + mi * 16 + ln;
            af[mi] = *(const bf16x8*)&As[r * 32 + ((hi ^ (r & 3)) << 3)];
        }
        #pragma unroll
        for (int ni = 0; ni < 4; ++ni) {
            int r = wc + ni * 16 + ln;
            bf[ni] = *(const bf16x8*)&Bs[r * 32 + ((hi ^ (r & 3)) << 3)];
        }
        #pragma unroll
        for (int mi = 0; mi < 4; ++mi)
            #pragma unroll
            for (int ni = 0; ni < 4; ++ni)
                acc[mi][ni] = MFMA16(af[mi], bf[ni], acc[mi][ni]);
    }

    #pragma unroll
    for (int mi = 0; mi < 4; ++mi) {
        #pragma unroll
        for (int ni = 0; ni < 4; ++ni) {
            int col = m0 + wc + ni * 16 + ln;
            float bv = bias[col];
            #pragma unroll
            for (int r = 0; r < 4; ++r) {
                int row = n0 + wr + mi * 16 + hi * 4 + r;
                float v = acc[mi][ni][r] + bv;
                if constexpr (sizeof(OutT) == 4) C[(size_t)row * MD + col] = v;
                else                             C[(size_t)row * MD + col] = (OutT)f2bf(v);
            }
        }
    }
}

// ---------------- MFMA flash attention (bf16), fully DMA-staged K and V^T,
// 2-phase double buffer (issue next-tile DMA before compute; __syncthreads'
// vmcnt(0)+barrier drains it after compute).
__global__ __launch_bounds__(256) void attn_mfma(const u16* __restrict__ qkv,
                                                 const u16* __restrict__ vtg,
                                                 u16* __restrict__ ctx) {
    __shared__ u16 Ks[2][64 * 64];  // [key][8B chunk c], c holds global c^(key&7) (8B units via 16B DMA)
    __shared__ u16 Vs[2][64 * 64];  // [d][8B chunk p], p holds src 8B chunk p^((d&7)<<1)
    const int bh = blockIdx.x;
    const int qt = 31 - blockIdx.y;          // longest-first (LPT)
    const int b = bh >> 4, h = bh & 15;
    const int t = threadIdx.x, w = t >> 6, lane = t & 63;
    const int ln = lane & 15, hi = lane >> 4;
    const int qrow = qt * 64 + w * 16 + ln;
    const size_t tok = (size_t)b * SS;

    // Q fragment (B operand of S^T): k = t2*32 + hi*8 + i, scaled by 1/8
    bf16x8 qb[2];
    #pragma unroll
    for (int t2 = 0; t2 < 2; ++t2) {
        bf16x8 v = *(const bf16x8*)&qkv[(tok + qrow) * 3072 + h * 64 + t2 * 32 + hi * 8];
        #pragma unroll
        for (int i = 0; i < 8; ++i)
            v[i] = (short)f2bf(bf2f((u16)v[i]) * 0.125f);
        qb[t2] = v;
    }

    float m_run = -1e30f, l_run = 0.f;
    f32x4 o[4];
    const f32x4 fz = {0.f, 0.f, 0.f, 0.f};
    #pragma unroll
    for (int i = 0; i < 4; ++i) o[i] = fz;

    // staging lane maps
    const int kkey_l = w * 8 + (lane >> 3);            // K row, + p*32
    const int ksch   = lane & 7;                        // K 16B chunk
    const int vrow_l = lane >> 3;                       // V row within 8-group
    const int vsch   = (lane & 7) ^ (lane >> 3);        // pre-swizzled V src 16B chunk

    const size_t vbase = (size_t)bh * 64 * SS;

    // prologue: stage tile 0 into buffer 0
    {
        const size_t kvb = (tok /*+ 0*/) * 3072 + h * 64;
        #pragma unroll
        for (int p = 0; p < 2; ++p) {
            int kk = p * 32 + kkey_l;
            gl_lds16(&qkv[kvb + (size_t)kk * 3072 + 1024 + ((ksch ^ (kk & 7)) << 3)],
                     &Ks[0][(p * 32 + w * 8) * 64]);
            int d = w * 16 + p * 8 + vrow_l;
            gl_lds16(&vtg[vbase + (size_t)d * SS + (vsch << 3)],
                     &Vs[0][(w * 16 + p * 8) * 64]);
        }
    }

    for (int kt = 0; kt <= qt; ++kt) {
        const int cur = kt & 1;
        __syncthreads();   // drains DMA for buf[cur] (vmcnt0 before barrier) + syncs readers

        if (kt < qt) {     // issue next-tile DMA into the other buffer
            const int nxt = cur ^ 1;
            const size_t kvb = (tok + (kt + 1) * 64) * 3072 + h * 64;
            #pragma unroll
            for (int p = 0; p < 2; ++p) {
                int kk = p * 32 + kkey_l;
                gl_lds16(&qkv[kvb + (size_t)kk * 3072 + 1024 + ((ksch ^ (kk & 7)) << 3)],
                         &Ks[nxt][(p * 32 + w * 8) * 64]);
                int d = w * 16 + p * 8 + vrow_l;
                gl_lds16(&vtg[vbase + (size_t)d * SS + (kt + 1) * 64 + (vsch << 3)],
                         &Vs[nxt][(w * 16 + p * 8) * 64]);
            }
        }

        // S^T = K . Q^T : 4 key sub-tiles of 16
        f32x4 sacc[4];
        #pragma unroll
        for (int s = 0; s < 4; ++s) {
            int key = s * 16 + ln;
            f32x4 a = fz;
            #pragma unroll
            for (int t2 = 0; t2 < 2; ++t2) {
                bf16x8 kf = *(const bf16x8*)&Ks[cur][key * 64 + (((t2 * 4 + hi) ^ (key & 7)) << 3)];
                a = MFMA16(kf, qb[t2], a);
            }
            sacc[s] = a;
        }

        // online softmax (lane owns one q-row; reduce over hi via 2 shfls)
        float p_[16];
        float mloc = -1e30f;
        if (kt == qt) {
            #pragma unroll
            for (int s = 0; s < 4; ++s)
                #pragma unroll
                for (int r = 0; r < 4; ++r) {
                    int keyg = kt * 64 + s * 16 + hi * 4 + r;
                    float v = (keyg <= qrow) ? sacc[s][r] : -1e30f;
                    p_[s * 4 + r] = v;
                    mloc = fmaxf(mloc, v);
                }
        } else {
            #pragma unroll
            for (int s = 0; s < 4; ++s)
                #pragma unroll
                for (int r = 0; r < 4; ++r) {
                    float v = sacc[s][r];
                    p_[s * 4 + r] = v;
                    mloc = fmaxf(mloc, v);
                }
        }
        mloc = fmaxf(mloc, __shfl_xor(mloc, 16));
        mloc = fmaxf(mloc, __shfl_xor(mloc, 32));
        float m_new = fmaxf(m_run, mloc);
        float alpha = __expf(m_run - m_new);
        float lsum = 0.f;
        #pragma unroll
        for (int i = 0; i < 16; ++i) {
            float e = __expf(p_[i] - m_new);
            p_[i] = e;
            lsum += e;
        }
        lsum += __shfl_xor(lsum, 16);
        lsum += __shfl_xor(lsum, 32);
        l_run = l_run * alpha + lsum;
        m_run = m_new;
        #pragma unroll
        for (int dt = 0; dt < 4; ++dt) o[dt] *= alpha;

        // P -> bf16 fragments via packed convert (identity key bijection)
        bf16x8 pa[2];
        #pragma unroll
        for (int k2 = 0; k2 < 2; ++k2) {
            union { unsigned wd[4]; bf16x8 v; } pu;
            #pragma unroll
            for (int qi = 0; qi < 4; ++qi)
                asm("v_cvt_pk_bf16_f32 %0, %1, %2"
                    : "=v"(pu.wd[qi])
                    : "v"(p_[k2 * 8 + 2 * qi]), "v"(p_[k2 * 8 + 2 * qi + 1]));
            pa[k2] = pu.v;
        }

        // O^T += V^T . P^T ; va slot i = V[key k2*32+16*(i>>2)+hi*4+(i&3)][d]
        #pragma unroll
        for (int dt = 0; dt < 4; ++dt) {
            const u16* row = &Vs[cur][(dt * 16 + ln) * 64];
            const int sw = (ln & 7) << 1;
            #pragma unroll
            for (int k2 = 0; k2 < 2; ++k2) {
                ushort4 lo4 = *(const ushort4*)&row[((k2 * 8 + hi)     ^ sw) * 4];
                ushort4 hi4 = *(const ushort4*)&row[((k2 * 8 + hi + 4) ^ sw) * 4];
                bf16x8 va;
                va[0] = (short)lo4.x; va[1] = (short)lo4.y; va[2] = (short)lo4.z; va[3] = (short)lo4.w;
                va[4] = (short)hi4.x; va[5] = (short)hi4.y; va[6] = (short)hi4.z; va[7] = (short)hi4.w;
                o[dt] = MFMA16(va, pa[k2], o[dt]);
            }
        }
    }

    // epilogue: lane owns qrow; d = dt*16 + hi*4 + r
    float inv = 1.f / l_run;
    #pragma unroll
    for (int dt = 0; dt < 4; ++dt) {
        ushort4 ov;
        ov.x = f2bf(o[dt][0] * inv);
        ov.y = f2bf(o[dt][1] * inv);
        ov.z = f2bf(o[dt][2] * inv);
        ov.w = f2bf(o[dt][3] * inv);
        *(ushort4*)&ctx[(tok + qrow) * 1024 + h * 64 + dt * 16 + hi * 4] = ov;
    }
}

extern "C" void kernel_launch(void* const* d_in, const int* in_sizes, int n_in,
                              void* d_out, int out_size, void* d_ws, size_t ws_size,
                              hipStream_t stream) {
    const float* hs     = (const float*)d_in[0];   // [2,2048,1024]
    const float* w_attn = (const float*)d_in[1];   // [1024,3072]
    const float* b_attn = (const float*)d_in[2];   // [3072]
    const float* w_proj = (const float*)d_in[3];   // [1024,1024]
    const float* b_proj = (const float*)d_in[4];   // [1024]
    float* out = (float*)d_out;                    // [2,2048,1024] fp32

    char* ws = (char*)d_ws;
    u16* hsb  = (u16*)ws;                          // 8 MB
    u16* waT  = (u16*)(ws + ((size_t)8  << 20));   // 6 MB  [3072][1024]
    u16* wpT  = (u16*)(ws + ((size_t)14 << 20));   // 2 MB  [1024][1024]
    u16* qkvb = (u16*)(ws + ((size_t)16 << 20));   // 24 MB [4096][3072]
    u16* ctxb = (u16*)(ws + ((size_t)40 << 20));   // 8 MB  [4096][1024]
    u16* vtg  = (u16*)(ws + ((size_t)48 << 20));   // 8 MB  [32*64][2048]

    cast_bf16<<<4096, 256, 0, stream>>>(hs, hsb, NT * 1024);
    transpose_cast<<<dim3(16, 48), 256, 0, stream>>>(w_attn, waT, 3072);
    transpose_cast<<<dim3(16, 16), 256, 0, stream>>>(w_proj, wpT, 1024);

    gemm_bt<3072, u16><<<dim3(NT / 128, 3072 / 128), 256, 0, stream>>>(hsb, waT, b_attn, qkvb);
    transpose_v<<<dim3(BB * 16, SS / 64), 256, 0, stream>>>(qkvb, vtg);
    attn_mfma<<<dim3(BB * 16, SS / 64), 256, 0, stream>>>(qkvb, vtg, ctxb);
    gemm_bt<1024, float><<<dim3(NT / 128, 1024 / 128), 256, 0, stream>>>(ctxb, wpT, b_proj, out);
}